// Round 1
// baseline (1587.158 us; speedup 1.0000x reference)
//
#include <hip/hip_runtime.h>
#include <stdint.h>

#define NPTS   32768
#define NBATCH 8
#define NFPS   512
#define NGRP   32
#define BIGF   1e10f
#define R2F    0.04f
#define CAP    512
#define QPB    8      // ball-query centroids per block

// ---------------------------------------------------------------------------
// FPS: ONE block per batch (P=1). No mailbox, no device-scope traffic, no
// spin loops -- the R14 mailbox exchange (~4000 cyc/iter of coherent RT)
// is replaced by 8x serial compute (~3100 cyc/iter VALU) + 2 barriers.
// 32 pts/thread: x,y,dist in VGPRs (96, asm-pinned vs remat -- R5/R6
// lesson), z in 128KB static LDS (read-only, contiguous ds_read_b128).
// Distance math bit-exact vs reference: contract off, (dx^2+dy^2)+dz^2,
// fminf accumulate; key (distbits<<32 | ~gi): max dist, ties -> min index;
// per-thread strict '>' in ascending local order keeps first occurrence
// (gi = 4096j + 4t + k is ascending in (j,k) for fixed t).
// Winner coords re-fetched from global (batch slice is L2-resident after
// the init read; ~220cy, off the old ~2us coherent path).
// float2 ext-vector arithmetic: if ISel emits v_pk_*_f32 the loop halves;
// scalar fallback is bit-identical.
// ---------------------------------------------------------------------------
#define THR    1024               // threads per fps block
#define NCH    8                  // float4-chunks per thread -> 32 pts/thread

typedef unsigned long long u64;
typedef float v2f __attribute__((ext_vector_type(2)));

__device__ __forceinline__ u64 shfl_xor_u64(u64 v, int off) {
    unsigned lo = (unsigned)v, hi = (unsigned)(v >> 32);
    lo = __shfl_xor(lo, off, 64);
    hi = __shfl_xor(hi, off, 64);
    return ((u64)hi << 32) | lo;
}

__global__ __launch_bounds__(THR) void fps_kernel(
    const float* __restrict__ xyz,
    const int* __restrict__ finit,
    int* __restrict__ cidx)        // [NBATCH][NFPS]
{
#pragma clang fp contract(off)
    const int b = blockIdx.x;
    const int t = threadIdx.x;
    const float* __restrict__ base = xyz + (size_t)b * (NPTS * 3);

    __shared__ float4 zs4[NPTS / 4];   // 128 KB: z coords, written once
    __shared__ u64 redK[16];
    __shared__ int farbox;

    v2f xr2[2 * NCH], yr2[2 * NCH], dist2[2 * NCH];   // 96 VGPRs persistent
    {
        const float4* __restrict__ g4 = reinterpret_cast<const float4*>(base);
#pragma unroll
        for (int j = 0; j < NCH; ++j) {
            const int c = j * THR + t;              // chunk: coalesced (48B/lane)
            const float4 q0 = g4[3 * c + 0];
            const float4 q1 = g4[3 * c + 1];
            const float4 q2 = g4[3 * c + 2];
            v2f a;
            a.x = q0.x; a.y = q0.w;  xr2[2 * j]     = a;   // x of pts 4c+0,1
            a.x = q1.z; a.y = q2.y;  xr2[2 * j + 1] = a;   // x of pts 4c+2,3
            a.x = q0.y; a.y = q1.x;  yr2[2 * j]     = a;
            a.x = q1.w; a.y = q2.z;  yr2[2 * j + 1] = a;
            zs4[c] = make_float4(q0.z, q1.y, q2.x, q2.w);
            a.x = BIGF; a.y = BIGF;
            dist2[2 * j] = a; dist2[2 * j + 1] = a;
        }
    }
    // pin coords into live VGPRs: an asm result cannot be rematerialized
    // (R5/R6: allocator otherwise re-issues the global loads per iteration)
#pragma unroll
    for (int i = 0; i < 2 * NCH; ++i) {
        asm("" : "+v"(xr2[i]), "+v"(yr2[i]));
    }

    int far = finit[b];
    float cx = base[3 * far + 0];
    float cy = base[3 * far + 1];
    float cz = base[3 * far + 2];

    const int wid  = t >> 6;
    const int lane = t & 63;
    __syncthreads();                    // zs4 published

    for (int it = 0; it < NFPS; ++it) {
        if (t == 0) cidx[b * NFPS + it] = far;   // record BEFORE update
        if (it == NFPS - 1) break;               // last far never used

        float vmax = -1.0f;
        int   amax = 0;
#pragma unroll
        for (int j = 0; j < NCH; ++j) {
            const float4 zq = zs4[j * THR + t];  // ds_read_b128, conflict-free
            {   // pair 0: local points 4j+0, 4j+1
                v2f z; z.x = zq.x; z.y = zq.y;
                v2f dx = xr2[2 * j] - cx;
                v2f dy = yr2[2 * j] - cy;
                v2f dz = z - cz;
                v2f s0 = dx * dx;
                v2f s1 = dy * dy;
                v2f d  = s0 + s1;
                v2f s2 = dz * dz;
                d = d + s2;
                float d0 = fminf(dist2[2 * j].x, d.x);
                float d1 = fminf(dist2[2 * j].y, d.y);
                dist2[2 * j].x = d0; dist2[2 * j].y = d1;
                if (d0 > vmax) { vmax = d0; amax = 4 * j + 0; }
                if (d1 > vmax) { vmax = d1; amax = 4 * j + 1; }
            }
            {   // pair 1: local points 4j+2, 4j+3
                v2f z; z.x = zq.z; z.y = zq.w;
                v2f dx = xr2[2 * j + 1] - cx;
                v2f dy = yr2[2 * j + 1] - cy;
                v2f dz = z - cz;
                v2f s0 = dx * dx;
                v2f s1 = dy * dy;
                v2f d  = s0 + s1;
                v2f s2 = dz * dz;
                d = d + s2;
                float d0 = fminf(dist2[2 * j + 1].x, d.x);
                float d1 = fminf(dist2[2 * j + 1].y, d.y);
                dist2[2 * j + 1].x = d0; dist2[2 * j + 1].y = d1;
                if (d0 > vmax) { vmax = d0; amax = 4 * j + 2; }
                if (d1 > vmax) { vmax = d1; amax = 4 * j + 3; }
            }
        }
        // local idx amax in [0,32) (inline-const friendly) -> global idx
        const int gi = ((amax >> 2) << 12) + (t << 2) + (amax & 3);
        u64 key = ((u64)__float_as_uint(vmax) << 32)
                | (u64)(0xFFFFFFFFu - (unsigned)gi);
#pragma unroll
        for (int off = 32; off >= 1; off >>= 1) {
            u64 o = shfl_xor_u64(key, off);
            key = (o > key) ? o : key;
        }
        if (lane == 0) redK[wid] = key;
        __syncthreads();                 // barrier 1: redK published

        if (wid == 0) {
            u64 k = redK[lane & 15];     // lanes 16..63 duplicate (xor-closed)
#pragma unroll
            for (int off = 8; off >= 1; off >>= 1) {
                u64 o = shfl_xor_u64(k, off);
                k = (o > k) ? o : k;
            }
            if (lane == 0)
                farbox = (int)(0xFFFFFFFFu - (unsigned)(k & 0xFFFFFFFFull));
        }
        __syncthreads();                 // barrier 2: winner published
        far = farbox;
        cx = base[3 * far + 0];          // L2-hot (slice loaded at init)
        cy = base[3 * far + 1];
        cz = base[3 * far + 2];
    }
}

// ---------------------------------------------------------------------------
// Ball query + grouping: QPB=8 centroids per block (unchanged, proven).
// ---------------------------------------------------------------------------
__global__ __launch_bounds__(256) void ballq_kernel(
    const float* __restrict__ xyz,
    const int* __restrict__ cidx,
    float* __restrict__ out0,      // [B][S][33][3]
    float* __restrict__ out1)      // [B][S][3]
{
#pragma clang fp contract(off)
    const int blk0 = blockIdx.x * QPB;   // first global centroid (b*NFPS+s)
    const int b    = blk0 >> 9;          // QPB divides 512 -> same batch
    const int t    = threadIdx.x;
    const float* __restrict__ base = xyz + (size_t)b * (NPTS * 3);

    __shared__ u64 list[QPB][CAP];       // 32 KB
    __shared__ int scnt[QPB];
    __shared__ u64 mask0[QPB];
    __shared__ int selIdx[QPB][NGRP];

    if (t < QPB) scnt[t] = 0;

    float cxs[QPB], cys[QPB], czs[QPB];
#pragma unroll
    for (int q = 0; q < QPB; ++q) {
        const int ci = cidx[blk0 + q];
        cxs[q] = base[3 * ci + 0];
        cys[q] = base[3 * ci + 1];
        czs[q] = base[3 * ci + 2];
    }
    __syncthreads();

    // in-ball masks for the first 64 indices (fill candidates); wave 0 only
    if (t < 64) {
        const float px = base[3 * t + 0];
        const float py = base[3 * t + 1];
        const float pz = base[3 * t + 2];
#pragma unroll
        for (int q = 0; q < QPB; ++q) {
            float dx = px - cxs[q];
            float dy = py - cys[q];
            float dz = pz - czs[q];
            float d  = dx * dx + dy * dy;
            d = d + dz * dz;
            u64 mk = __ballot(d <= R2F);
            if (t == 0) mask0[q] = mk;
        }
    }

    // scan all points once; test against all QPB centroids
    for (int k = 0; k < NPTS / 256; ++k) {
        const int p = k * 256 + t;
        const float px = base[3 * p + 0];
        const float py = base[3 * p + 1];
        const float pz = base[3 * p + 2];
#pragma unroll
        for (int q = 0; q < QPB; ++q) {
            float dx = px - cxs[q];
            float dy = py - cys[q];
            float dz = pz - czs[q];
            float d  = dx * dx + dy * dy;
            d = d + dz * dz;
            if (d <= R2F) {
                int pos = atomicAdd(&scnt[q], 1);
                if (pos < CAP)
                    list[q][pos] = (((u64)__float_as_uint(d)) << 32)
                                   | (unsigned)p;
            }
        }
    }
    __syncthreads();

    // rank-based selection, 2 centroids per wave:
    // key's rank == #smaller keys (keys unique via idx)
    {
        const int lane = t & 63;
        for (int q = t >> 6; q < QPB; q += 4) {
            const int m = min(scnt[q], CAP);
            for (int j = lane; j < m; j += 64) {
                const u64 kj = list[q][j];
                int rank = 0;
                for (int i = 0; i < m; ++i) rank += (list[q][i] < kj) ? 1 : 0;
                if (rank < NGRP) selIdx[q][rank] = (int)(kj & 0xffffffffu);
            }
        }
    }
    __syncthreads();

    for (int s = t; s < 33 * QPB; s += 256) {
        const int q    = s / 33;
        const int slot = s % 33;
        const int sg   = blk0 + q;
        const float cx = cxs[q], cy = cys[q], cz = czs[q];
        const size_t o0 = (size_t)sg * 33 * 3;
        if (slot == 32) {
            out0[o0 + 0] = cx; out0[o0 + 1] = cy; out0[o0 + 2] = cz;
            const size_t o1 = (size_t)sg * 3;
            out1[o1 + 0] = cx; out1[o1 + 1] = cy; out1[o1 + 2] = cz;
        } else {
            const int m = min(scnt[q], CAP);
            const int K = min(m, NGRP);
            int idx;
            if (slot < K) {
                idx = selIdx[q][slot];
            } else {
                // (slot-K+1)-th zero bit of mask0 = next out-of-radius index
                u64 zeros = ~mask0[q];
                const int need = slot - K;
                for (int z = 0; z < need; ++z) zeros &= zeros - 1;
                idx = __builtin_ctzll(zeros);
            }
            const float px = base[3 * idx + 0];
            const float py = base[3 * idx + 1];
            const float pz = base[3 * idx + 2];
            out0[o0 + (size_t)(1 + slot) * 3 + 0] = px - cx;
            out0[o0 + (size_t)(1 + slot) * 3 + 1] = py - cy;
            out0[o0 + (size_t)(1 + slot) * 3 + 2] = pz - cz;
        }
    }
}

extern "C" void kernel_launch(void* const* d_in, const int* in_sizes, int n_in,
                              void* d_out, int out_size, void* d_ws, size_t ws_size,
                              hipStream_t stream) {
    const float* xyz   = (const float*)d_in[0];
    const int*   finit = (const int*)d_in[1];
    float* out0 = (float*)d_out;
    float* out1 = out0 + (size_t)NBATCH * NFPS * 33 * 3;

    // ws layout: cidx 16 KB (mailbox no longer needed -- P=1 FPS)
    int* cidx = (int*)d_ws;

    fps_kernel<<<NBATCH, THR, 0, stream>>>(xyz, finit, cidx);
    ballq_kernel<<<(NBATCH * NFPS) / QPB, 256, 0, stream>>>(xyz, cidx, out0, out1);
}